// Round 12
// baseline (297.412 us; speedup 1.0000x reference)
//
#include <hip/hip_runtime.h>
#include <hip/hip_bf16.h>

#define SEQ   512
#define BATCH 128
#define FEAT  1024
#define EMBED 1024
#define NLANG 8

typedef __attribute__((ext_vector_type(8))) short bf16x8;
typedef __attribute__((ext_vector_type(4))) float f32x4;
typedef unsigned short ushort_t;

__device__ __forceinline__ unsigned pk2(float a, float b) {
  float2 f; f.x = a; f.y = b;
  __hip_bfloat162 h = __float22bfloat162_rn(f);   // v_cvt_pk_bf16_f32
  union { __hip_bfloat162 h2; unsigned u; } cv;
  cv.h2 = h;
  return cv.u;
}

__device__ __forceinline__ bf16x8 cvt8(float4 lo, float4 hi) {
  union { bf16x8 v; unsigned u[4]; } q;
  q.u[0] = pk2(lo.x, lo.y); q.u[1] = pk2(lo.z, lo.w);
  q.u[2] = pk2(hi.x, hi.y); q.u[3] = pk2(hi.z, hi.w);
  return q.v;
}

__device__ __forceinline__ void gld16(const void* g, void* l) {
  __builtin_amdgcn_global_load_lds(
      (const __attribute__((address_space(1))) void*)g,
      (__attribute__((address_space(3))) void*)l, 16, 0, 0);
}

// ---------------- Pass 1 (W only): f32 -> bf16, linear. ~48 MB traffic. -----
__global__ __launch_bounds__(256) void convert_w_kernel(
    const float* __restrict__ Wf, ushort_t* __restrict__ Wbf)
{
  const int n = (NLANG * EMBED * FEAT) / 4;
  for (int c = blockIdx.x * 256 + threadIdx.x; c < n; c += gridDim.x * 256) {
    float4 v = ((const float4*)Wf)[c];
    uint2 o; o.x = pk2(v.x, v.y); o.y = pk2(v.z, v.w);
    *(uint2*)(Wbf + ((size_t)c << 2)) = o;
  }
}

// ---------------- Pass 2: R10's verified 16-wave 256x256 GEMM with ONE delta:
// A comes from f32 feat via regs + cvt + ds_write (R11-clean bf16 layout,
// A ring-2), B via gld16 ring-3 (unchanged). 1024 threads = 16 waves (4Mx4N),
// 1 block/CU (80 KiB LDS), counted vmcnt, setprio, XCD swizzle.
// Ledger per body t (issue order: WRITE_A(t+1)[cvt waits A-regs], LOAD_A(t+2)
// x2, STAGE_B(t+2)x1): top outstanding = A(t+1)x2,B(t+1)x1 -> cvt implicit
// vmcnt(1); end outstanding = B(t+1),A(t+2)x2,B(t+2) -> vmcnt(3) retires
// exactly B(t+1); lgkmcnt(0) publishes the ds_write before the barrier.
__global__ __launch_bounds__(1024, 4) void grouped_gemm_fused16(
    const float* __restrict__ feat,    // [S*B, F] f32 (original order)
    const ushort_t* __restrict__ Wbf,  // [L, E, F] bf16
    const float* __restrict__ bias,    // [L, E]
    const int*   __restrict__ toks,    // [B]
    float*       __restrict__ out)     // [S*B, E] original order
{
  extern __shared__ ushort_t lds[];          // 40960 ushort = 80 KiB
  // A: bufs 0,1 at lds[buf*8192]; B: bufs 0..2 at lds[16384 + buf*8192].
  __shared__ int tokarr[128];
  __shared__ unsigned long long ballots[2][8];
  __shared__ int perm[128];
  __shared__ int rowsrc[256];

  const int tid = threadIdx.x;
  const int l   = tid & 63;
  const int w   = tid >> 6;                  // 0..15
  const int wr  = w >> 2;                    // 0..3 (M quarter)
  const int wc  = w & 3;                     // 0..3 (N quarter)

  // XCD-chunked bijective swizzle (1024 blocks = 8 XCDs x 128).
  const int bid = blockIdx.x;
  const int L   = (bid & 7) * 128 + (bid >> 3);
  const int et  = L & 3;
  const int mt  = (L >> 7) * 32 + ((L >> 2) & 31);
  const int m0  = mt * 256;
  const int e0  = et * 256;

  // ---- bucket setup (ballot histogram + rank; waves 0,1 vote) ----
  if (tid < 128) tokarr[tid] = toks[tid];
  __syncthreads();
  if (tid < 128) {
    int myt = tokarr[tid];
#pragma unroll
    for (int lg = 0; lg < 8; ++lg) {
      unsigned long long bl = __ballot(myt == lg);
      if (l == 0) ballots[w][lg] = bl;
    }
  }
  __syncthreads();

  int lsel = 0, base = 0, csel = 1, boff_sel = 0;
  {
    int cum = 0, boff = 0;
#pragma unroll
    for (int lg = 0; lg < 8; ++lg) {
      int c = __popcll(ballots[0][lg]) + __popcll(ballots[1][lg]);
      int seg = c << 9;
      bool in = (m0 >= cum) && (m0 < cum + seg);
      if (in) { lsel = lg; base = cum; csel = c; boff_sel = boff; }
      cum += seg; boff += c;
    }
  }

  if (tid < 128) {
    int myt = tokarr[tid];
    unsigned long long ltm = (1ull << l) - 1ull;
    int rank = (w == 0) ? __popcll(ballots[0][myt] & ltm)
                        : __popcll(ballots[0][myt]) + __popcll(ballots[1][myt] & ltm);
    int boff2 = 0;
#pragma unroll
    for (int lg = 0; lg < 8; ++lg) {
      int c = __popcll(ballots[0][lg]) + __popcll(ballots[1][lg]);
      boff2 += (lg < myt) ? c : 0;
    }
    perm[boff2 + rank] = tid;
  }
  __syncthreads();
  if (tid < 256) {
    int local = m0 - base + tid;
    int s = local / csel;
    int j = local - s * csel;
    rowsrc[tid] = s * BATCH + perm[boff_sel + j];
  }
  __syncthreads();

  // ---- A reg-staging: granule = 256 rows x 32 k. bf16 chunk (row, cc)
  // holds global k-chunk cc^((row>>1)&3) (R10's exact layout; swizzle folded
  // into the f32 SOURCE). Thread owns chunk tid: row = tid>>2, cc = tid&3;
  // source = 8 f32 (2x dwordx4, 4 lanes/row -> 128B coalesced). ds_write
  // dest lane-sequential (2-way banks, free). ----
  const int arow = tid >> 2;
  const int acck = tid & 3;
  const int sAk  = (arow >> 1) & 3;
  const float* aSrcP = feat + (size_t)rowsrc[arow] * FEAT + ((acck ^ sAk) * 8);
  const int wchunk = tid;                    // bf16x8 index within A buf
  float4 ar0, ar1;                           // in-flight A regs (1 set)

  // ---- B staging (R10-verified): chunk tid: rwB = tid>>2, ccB = tid&3;
  // src chunk = ccB ^ ((rwB>>1)&3); dest lane-sequential per wave. ----
  const int rwB = tid >> 2;
  const int ccB = tid & 3;
  const int sBk = (rwB >> 1) & 3;
  const ushort_t* bS = Wbf + ((size_t)lsel * EMBED + e0 + rwB) * FEAT + ((ccB ^ sBk) * 8);
  const int dOffB = w * 512;                 // ushort units within a B buf

  // ---- fragment read offsets (R10-verified, conflict-free) ----
  const int kc  = l >> 4;
  const int rA  = wr * 64 + (l & 15);
  const int aRd = rA * 32 + ((kc ^ ((rA >> 1) & 3)) * 8);
  const int rB  = wc * 64 + (l & 15);
  const int bRd = rB * 32 + ((kc ^ ((rB >> 1) & 3)) * 8);

  f32x4 acc[4][4] = {};

#define LOAD_A(kt)                                                         \
  do { const float* _p = aSrcP + (kt) * 32;                                \
    ar0 = *(const float4*)(_p); ar1 = *(const float4*)(_p + 4); } while (0)
#define WRITE_A(abuf)                                                      \
  do { ((bf16x8*)(lds + (abuf) * 8192))[wchunk] = cvt8(ar0, ar1); } while (0)
#define STAGE_B(kt, bbuf)                                                  \
  do { gld16(bS + (kt) * 32, lds + 16384 + (bbuf) * 8192 + dOffB); } while (0)

// Body t: AJ = t&1 (A read buf), BJ = t%3 (B read buf); compile-time via
// period-6 unroll. Steady: WRITE_A(t+1 -> A buf AJ^1) at TOP, then
// LOAD_A(t+2) + STAGE_B(t+2 -> B buf (BJ+2)%3), frags from bufs AJ/BJ,
// 16 MFMA, ENDWAIT, barrier.
#define BODY(t, AJ, BJ, DOWRITE, DOLOAD, ENDWAIT, ENDBAR)                  \
  do {                                                                     \
    if (DOWRITE) { WRITE_A((AJ) ^ 1); }                                    \
    if (DOLOAD)  { LOAD_A((t) + 2); STAGE_B((t) + 2, ((BJ) + 2) % 3); }    \
    const ushort_t* Ar_ = lds + (AJ) * 8192;                               \
    const ushort_t* Br_ = lds + 16384 + (BJ) * 8192;                       \
    bf16x8 af[4], bfq[4];                                                  \
    _Pragma("unroll") for (int mf = 0; mf < 4; ++mf)                       \
        af[mf] = *(const bf16x8*)(Ar_ + aRd + mf * 512);                   \
    _Pragma("unroll") for (int nf = 0; nf < 4; ++nf)                       \
        bfq[nf] = *(const bf16x8*)(Br_ + bRd + nf * 512);                  \
    __builtin_amdgcn_s_setprio(1);                                         \
    _Pragma("unroll") for (int mf = 0; mf < 4; ++mf)                       \
        _Pragma("unroll") for (int nf = 0; nf < 4; ++nf)                   \
            acc[mf][nf] = __builtin_amdgcn_mfma_f32_16x16x32_bf16(         \
                af[mf], bfq[nf], acc[mf][nf], 0, 0, 0);                    \
    __builtin_amdgcn_s_setprio(0);                                         \
    asm volatile(ENDWAIT ::: "memory");                                    \
    if (ENDBAR) { __builtin_amdgcn_s_barrier();                            \
                  __builtin_amdgcn_sched_barrier(0); }                     \
  } while (0)

  // ---- prologue: A(0)->regs->cvt->Abuf0; A(1)->regs; B(0),B(1) staged.
  // In-order outstanding at wait: A(1)x2, B(0), B(1) -> vmcnt(1) retires
  // B(0) (and A(1), issued earlier); lgkm publishes Abuf0. ----
  LOAD_A(0);
  WRITE_A(0);
  LOAD_A(1);
  STAGE_B(0, 0);
  STAGE_B(1, 1);
  asm volatile("s_waitcnt vmcnt(1) lgkmcnt(0)" ::: "memory");
  __builtin_amdgcn_s_barrier();
  __builtin_amdgcn_sched_barrier(0);

  // ---- main: bodies 0..29, period-6 unroll (AJ = t&1, BJ = t%3) ----
#pragma unroll 1
  for (int gb = 0; gb < 30; gb += 6) {
    BODY(gb + 0, 0, 0, true, true, "s_waitcnt vmcnt(3) lgkmcnt(0)", true);
    BODY(gb + 1, 1, 1, true, true, "s_waitcnt vmcnt(3) lgkmcnt(0)", true);
    BODY(gb + 2, 0, 2, true, true, "s_waitcnt vmcnt(3) lgkmcnt(0)", true);
    BODY(gb + 3, 1, 0, true, true, "s_waitcnt vmcnt(3) lgkmcnt(0)", true);
    BODY(gb + 4, 0, 1, true, true, "s_waitcnt vmcnt(3) lgkmcnt(0)", true);
    BODY(gb + 5, 1, 2, true, true, "s_waitcnt vmcnt(3) lgkmcnt(0)", true);
  }
  // tail: body 30 (AJ=0,BJ=0): WRITE_A(31)->Abuf1, no loads; drain all VMEM.
  BODY(30, 0, 0, true, false, "s_waitcnt vmcnt(0) lgkmcnt(0)", true);
  // body 31 (AJ=1,BJ=1): compute only.
  BODY(31, 1, 1, false, false, "s_nop 0", false);

#undef BODY
#undef LOAD_A
#undef WRITE_A
#undef STAGE_B

  // ---- epilogue: C/D col = lane&15 (-> e), row = (lane>>4)*4+j (-> m) ----
  const int col = l & 15;
  const int r4  = (l >> 4) * 4;
  float bvv[4];
#pragma unroll
  for (int nf = 0; nf < 4; ++nf)
    bvv[nf] = bias[lsel * EMBED + e0 + wc * 64 + nf * 16 + col];
#pragma unroll
  for (int mf = 0; mf < 4; ++mf) {
#pragma unroll
    for (int j = 0; j < 4; ++j) {
      const size_t ro = (size_t)rowsrc[wr * 64 + mf * 16 + r4 + j] * EMBED;
#pragma unroll
      for (int nf = 0; nf < 4; ++nf)
        out[ro + e0 + wc * 64 + nf * 16 + col] = acc[mf][nf][j] + bvv[nf];
    }
  }
}

// ---------------- Fallback (R2 fused kernel) if ws too small ----------------
__global__ __launch_bounds__(256, 2) void grouped_proj_fused(
    const float* __restrict__ feat, const float* __restrict__ Wt,
    const float* __restrict__ bias, const int* __restrict__ toks,
    float* __restrict__ out)
{
  __shared__ uint4 As[1024];
  __shared__ uint4 Bs[1024];
  __shared__ int tokarr[128];
  __shared__ unsigned long long ballots[2][8];
  __shared__ int perm[128];
  __shared__ int rowsrc[128];

  const int tid  = threadIdx.x;
  const int lane = tid & 63;
  const int wv   = tid >> 6;
  const int wr   = wv >> 1;
  const int wc   = wv & 1;
  const int bid = blockIdx.x;
  const int xcd = bid & 7;
  const int sq  = bid >> 3;
  const int et  = sq & 7;
  const int mt  = (sq >> 3) * 8 + xcd;
  const int m0  = mt * 128;
  const int e0  = et * 128;

  if (tid < 128) tokarr[tid] = toks[tid];
  __syncthreads();
  if (tid < 128) {
    int myt = tokarr[tid];
#pragma unroll
    for (int lg = 0; lg < 8; ++lg) {
      unsigned long long bl = __ballot(myt == lg);
      if (lane == 0) ballots[wv][lg] = bl;
    }
  }
  __syncthreads();
  int lsel = 0, base = 0, csel = 1, boff_sel = 0;
  {
    int cum = 0, boff = 0;
#pragma unroll
    for (int lg = 0; lg < 8; ++lg) {
      int c = __popcll(ballots[0][lg]) + __popcll(ballots[1][lg]);
      int seg = c << 9;
      bool in = (m0 >= cum) && (m0 < cum + seg);
      if (in) { lsel = lg; base = cum; csel = c; boff_sel = boff; }
      cum += seg; boff += c;
    }
  }
  if (tid < 128) {
    int myt = tokarr[tid];
    unsigned long long ltm = (1ull << lane) - 1ull;
    int rank = (wv == 0) ? __popcll(ballots[0][myt] & ltm)
                         : __popcll(ballots[0][myt]) + __popcll(ballots[1][myt] & ltm);
    int boff2 = 0;
#pragma unroll
    for (int lg = 0; lg < 8; ++lg) {
      int c = __popcll(ballots[0][lg]) + __popcll(ballots[1][lg]);
      boff2 += (lg < myt) ? c : 0;
    }
    perm[boff2 + rank] = tid;
  }
  __syncthreads();
  if (tid < 128) {
    int local = m0 - base + tid;
    int s = local / csel;
    int j = local - s * csel;
    rowsrc[tid] = s * BATCH + perm[boff_sel + j];
  }
  __syncthreads();

  int slot_i[4];
  const float* aptr[4];
  const float* bptr[4];
#pragma unroll
  for (int it = 0; it < 4; ++it) {
    int c    = it * 256 + tid;
    int kg   = c & 7;
    int row  = c >> 3;
    int ksub = kg & 3;
    int kk   = kg >> 2;
    int frag = row >> 4;
    slot_i[it] = (kk * 8 + frag) * 64 + ((row & 15) ^ (ksub << 1) ^ kk) + ksub * 16;
    aptr[it] = feat + (size_t)rowsrc[row] * FEAT + kg * 8;
    bptr[it] = Wt + ((size_t)lsel * EMBED + e0 + row) * FEAT + kg * 8;
  }

  f32x4 acc[4][4] = {};
  for (int k0 = 0; k0 < FEAT; k0 += 64) {
    __syncthreads();
#pragma unroll
    for (int it = 0; it < 4; ++it) {
      float4 alo = *(const float4*)(aptr[it] + k0);
      float4 ahi = *(const float4*)(aptr[it] + k0 + 4);
      uint4 av;
      av.x = pk2(alo.x, alo.y); av.y = pk2(alo.z, alo.w);
      av.z = pk2(ahi.x, ahi.y); av.w = pk2(ahi.z, ahi.w);
      As[slot_i[it]] = av;
      float4 blo = *(const float4*)(bptr[it] + k0);
      float4 bhi = *(const float4*)(bptr[it] + k0 + 4);
      uint4 bv;
      bv.x = pk2(blo.x, blo.y); bv.y = pk2(blo.z, blo.w);
      bv.z = pk2(bhi.x, bhi.y); bv.w = pk2(bhi.z, bhi.w);
      Bs[slot_i[it]] = bv;
    }
    __syncthreads();
#pragma unroll
    for (int kk = 0; kk < 2; ++kk) {
      const int ksr = lane >> 4;
      const int sw  = ((lane & 15) ^ (ksr << 1) ^ kk) + ksr * 16;
      bf16x8 af[4], bfr[4];
#pragma unroll
      for (int mi = 0; mi < 4; ++mi)
        af[mi] = ((const bf16x8*)As)[(kk * 8 + wr * 4 + mi) * 64 + sw];
#pragma unroll
      for (int ni = 0; ni < 4; ++ni)
        bfr[ni] = ((const bf16x8*)Bs)[(kk * 8 + wc * 4 + ni) * 64 + sw];
#pragma unroll
      for (int mi = 0; mi < 4; ++mi)
#pragma unroll
        for (int ni = 0; ni < 4; ++ni)
          acc[mi][ni] = __builtin_amdgcn_mfma_f32_16x16x32_bf16(
              af[mi], bfr[ni], acc[mi][ni], 0, 0, 0);
    }
  }

  const int col = lane & 15;
  const int r0  = (lane >> 4) * 4;
  float bvv[4];
#pragma unroll
  for (int ni = 0; ni < 4; ++ni)
    bvv[ni] = bias[lsel * EMBED + e0 + wc * 64 + ni * 16 + col];
#pragma unroll
  for (int mi = 0; mi < 4; ++mi) {
#pragma unroll
    for (int j = 0; j < 4; ++j) {
      const size_t ro = (size_t)rowsrc[wr * 64 + mi * 16 + r0 + j] * EMBED;
#pragma unroll
      for (int ni = 0; ni < 4; ++ni)
        out[ro + e0 + wc * 64 + ni * 16 + col] = acc[mi][ni][j] + bvv[ni];
    }
  }
}

extern "C" void kernel_launch(void* const* d_in, const int* in_sizes, int n_in,
                              void* d_out, int out_size, void* d_ws, size_t ws_size,
                              hipStream_t stream) {
  const float* feat = (const float*)d_in[0];
  const float* W    = (const float*)d_in[1];
  const float* bias = (const float*)d_in[2];
  const int*   toks = (const int*)d_in[3];
  float* out = (float*)d_out;

  const size_t wbf_bytes = (size_t)NLANG * EMBED * FEAT * 2;      // 16 MiB

  if (ws_size >= wbf_bytes) {
    ushort_t* Wbf = (ushort_t*)d_ws;
    convert_w_kernel<<<512, 256, 0, stream>>>(W, Wbf);
    (void)hipFuncSetAttribute((const void*)grouped_gemm_fused16,
                              hipFuncAttributeMaxDynamicSharedMemorySize, 81920);
    const int nblk = (SEQ * BATCH / 256) * (EMBED / 256);         // 1024
    grouped_gemm_fused16<<<nblk, 1024, 81920, stream>>>(feat, Wbf, bias, toks, out);
  } else {
    grouped_proj_fused<<<(SEQ * BATCH / 128) * (EMBED / 128), 256, 0, stream>>>(
        feat, W, bias, toks, out);
  }
}

// Round 14
// 248.146 us; speedup vs baseline: 1.1985x; 1.1985x over previous
//
#include <hip/hip_runtime.h>
#include <hip/hip_bf16.h>

#define SEQ   512
#define BATCH 128
#define FEAT  1024
#define EMBED 1024
#define NLANG 8

typedef __attribute__((ext_vector_type(8))) short bf16x8;
typedef __attribute__((ext_vector_type(4))) float f32x4;
typedef unsigned short ushort_t;

__device__ __forceinline__ unsigned pk2(float a, float b) {
  float2 f; f.x = a; f.y = b;
  __hip_bfloat162 h = __float22bfloat162_rn(f);   // v_cvt_pk_bf16_f32
  union { __hip_bfloat162 h2; unsigned u; } cv;
  cv.h2 = h;
  return cv.u;
}

__device__ __forceinline__ bf16x8 cvt8(f32x4 lo, f32x4 hi) {
  union { bf16x8 v; unsigned u[4]; } q;
  q.u[0] = pk2(lo[0], lo[1]); q.u[1] = pk2(lo[2], lo[3]);
  q.u[2] = pk2(hi[0], hi[1]); q.u[3] = pk2(hi[2], hi[3]);
  return q.v;
}

__device__ __forceinline__ void gld16(const void* g, void* l) {
  __builtin_amdgcn_global_load_lds(
      (const __attribute__((address_space(1))) void*)g,
      (__attribute__((address_space(3))) void*)l, 16, 0, 0);
}

// ---------------- Pass 1 (W only): f32 -> bf16, linear. ~48 MB traffic. -----
__global__ __launch_bounds__(256) void convert_w_kernel(
    const float* __restrict__ Wf, ushort_t* __restrict__ Wbf)
{
  const int n = (NLANG * EMBED * FEAT) / 4;
  for (int c = blockIdx.x * 256 + threadIdx.x; c < n; c += gridDim.x * 256) {
    float4 v = ((const float4*)Wf)[c];
    uint2 o; o.x = pk2(v.x, v.y); o.y = pk2(v.z, v.w);
    *(uint2*)(Wbf + ((size_t)c << 2)) = o;
  }
}

// ---------------- Pass 2: fused grouped GEMM, convert-once-in-LDS ----------
// (R13 with the STAGE_A dest-offset fix: aD is ushort units, no *2.)
// 256x256 tile, BK=32 granules, 512 threads = 8 waves (2M x 4N), wave =
// 128x64 via acc[8][4]. A: gld16 stages f32 granule LINEARLY (ring-2, 64KiB);
// per-granule CONV phase: each thread reads 4 lane-sequential b128 chunks
// (conflict-free by construction), cvt ONCE (1x redundancy), ds_write into
// the R4/R10-measured-clean bf16 layout (16KiB single buf); MFMA fragments
// read only bf16. B: bf16 gld16 ring-3 (48KiB, R4-verified). LDS=128KiB.
// Ledger: 6 VMEM/granule (A x4 + B x2); steady end-wait vmcnt(6) retires
// granule t+1; conv publishes via lgkmcnt(0)+barrier; Abf16 WAR-safe (frag
// reads drain at the pre-MFMA lgkm; next conv writes after the end barrier).
__global__ __launch_bounds__(512, 2) void grouped_gemm_cvt1(
    const float* __restrict__ feat,    // [S*B, F] f32 (original order)
    const ushort_t* __restrict__ Wbf,  // [L, E, F] bf16
    const float* __restrict__ bias,    // [L, E]
    const int*   __restrict__ toks,    // [B]
    float*       __restrict__ out)     // [S*B, E] original order
{
  extern __shared__ ushort_t lds[];   // 65536 us = 128 KiB:
  // A-f32: [0, 32768) us, 2 bufs x 16384 us (32 KiB each)
  // A-bf16: [32768, 40960) us, 1 buf (16 KiB)
  // B: [40960, 65536) us, 3 bufs x 8192 us (16 KiB each)
  __shared__ int tokarr[128];
  __shared__ unsigned long long ballots[2][8];
  __shared__ int perm[128];
  __shared__ int rowsrc[256];

  const int tid = threadIdx.x;
  const int l   = tid & 63;
  const int w   = tid >> 6;
  const int wr  = w >> 2;                    // 0..1 (M half)
  const int wc  = w & 3;                     // 0..3 (N quarter)

  // XCD-chunked bijective swizzle (1024 blocks = 8 XCDs x 128).
  const int bid = blockIdx.x;
  const int L   = (bid & 7) * 128 + (bid >> 3);
  const int et  = L & 3;
  const int mt  = (L >> 7) * 32 + ((L >> 2) & 31);
  const int m0  = mt * 256;
  const int e0  = et * 256;

  // ---- bucket setup (ballot histogram + rank; waves 0,1 vote) ----
  if (tid < 128) tokarr[tid] = toks[tid];
  __syncthreads();
  if (tid < 128) {
    int myt = tokarr[tid];
#pragma unroll
    for (int lg = 0; lg < 8; ++lg) {
      unsigned long long bl = __ballot(myt == lg);
      if (l == 0) ballots[w][lg] = bl;
    }
  }
  __syncthreads();

  int lsel = 0, base = 0, csel = 1, boff_sel = 0;
  {
    int cum = 0, boff = 0;
#pragma unroll
    for (int lg = 0; lg < 8; ++lg) {
      int c = __popcll(ballots[0][lg]) + __popcll(ballots[1][lg]);
      int seg = c << 9;
      bool in = (m0 >= cum) && (m0 < cum + seg);
      if (in) { lsel = lg; base = cum; csel = c; boff_sel = boff; }
      cum += seg; boff += c;
    }
  }

  if (tid < 128) {
    int myt = tokarr[tid];
    unsigned long long ltm = (1ull << l) - 1ull;
    int rank = (w == 0) ? __popcll(ballots[0][myt] & ltm)
                        : __popcll(ballots[0][myt]) + __popcll(ballots[1][myt] & ltm);
    int boff2 = 0;
#pragma unroll
    for (int lg = 0; lg < 8; ++lg) {
      int c = __popcll(ballots[0][lg]) + __popcll(ballots[1][lg]);
      boff2 += (lg < myt) ? c : 0;
    }
    perm[boff2 + rank] = tid;
  }
  __syncthreads();
  if (tid < 256) {
    int local = m0 - base + tid;
    int s = local / csel;
    int j = local - s * csel;
    rowsrc[tid] = s * BATCH + perm[boff_sel + j];
  }
  __syncthreads();

  // ---- A-f32 staging (LINEAR): granule = 256 rows x 32 f32 = 2048 chunks
  // of 16B; chunk f = row*8 + gk (row-major). Wave w, instr i covers chunks
  // (w*4+i)*64 + l -> row = w*32 + i*8 + (l>>3), gk = l&7 (8 lanes/row =
  // 128B coalesced). Dest ushort offset = chunkbase*8 = (w*4+i)*512. ----
  const float* aS[4];
#pragma unroll
  for (int i = 0; i < 4; ++i) {
    const int row = w * 32 + i * 8 + (l >> 3);
    aS[i] = feat + (size_t)rowsrc[row] * FEAT + (l & 7) * 4;
  }
  const int aD[4] = { (w * 4 + 0) * 512, (w * 4 + 1) * 512,
                      (w * 4 + 2) * 512, (w * 4 + 3) * 512 };  // ushort units

  // ---- CONV assignment: thread t owns f32 chunks 4t..4t+3 (= row r=t>>1,
  // k-half h=t&1, gks 4h..4h+3) -> bf16 chunks j=2h,2h+1 stored at
  // c = r*4 + (j ^ ((r>>1)&3))  (R4/R10 layout: chunk (r,cc) holds k-chunk
  // cc^s). ds_read lane-sequential; ds_write covers all 8 bank-quads 2x. ----
  const int cr  = tid >> 1;
  const int chh = tid & 1;
  const int csw = (cr >> 1) & 3;
  const int wc0 = cr * 4 + ((2 * chh) ^ csw);
  const int wc1 = cr * 4 + ((2 * chh + 1) ^ csw);

  // ---- B staging (R4-verified): granule = 1024 chunks; wave w owns chunks
  // w*128+l, +64; src k-chunk = cc ^ ((row>>1)&3). ----
  const int ca  = w * 128 + l;
  const int rwB = ca >> 2;
  const int ccB = ca & 3;
  const int sB  = (rwB >> 1) & 3;
  const ushort_t* bS0 = Wbf + ((size_t)lsel * EMBED + e0 + rwB) * FEAT + ((ccB ^ sB) * 8);
  const ushort_t* bS1 = bS0 + (size_t)16 * FEAT;
  const int bD0 = (w * 128) * 8;
  const int bD1 = (w * 128 + 64) * 8;

  // ---- fragment read offsets (R4-verified, conflict-free bf16 family) ----
  const int kc  = l >> 4;
  const int rA  = wr * 128 + (l & 15);
  const int aRd = rA * 32 + ((kc ^ ((rA >> 1) & 3)) * 8);
  const int rB  = wc * 64 + (l & 15);
  const int bRd = rB * 32 + ((kc ^ ((rB >> 1) & 3)) * 8);

  f32x4 acc[8][4] = {};

#define STAGE_A(kt, abuf)                                                  \
  do { const int _o = (kt) * 32;                                           \
    gld16(aS[0] + _o, lds + (abuf) * 16384 + aD[0]);                       \
    gld16(aS[1] + _o, lds + (abuf) * 16384 + aD[1]);                       \
    gld16(aS[2] + _o, lds + (abuf) * 16384 + aD[2]);                       \
    gld16(aS[3] + _o, lds + (abuf) * 16384 + aD[3]); } while (0)
#define STAGE_B(kt, bbuf)                                                  \
  do { const int _o = (kt) * 32;                                           \
    gld16(bS0 + _o, lds + 40960 + (bbuf) * 8192 + bD0);                    \
    gld16(bS1 + _o, lds + 40960 + (bbuf) * 8192 + bD1); } while (0)
#define CONV(abuf)                                                         \
  do {                                                                     \
    const f32x4* _fp = (const f32x4*)(lds + (abuf) * 16384);               \
    f32x4 q0 = _fp[4 * tid + 0], q1 = _fp[4 * tid + 1];                    \
    f32x4 q2 = _fp[4 * tid + 2], q3 = _fp[4 * tid + 3];                    \
    bf16x8* _bp = (bf16x8*)(lds + 32768);                                  \
    _bp[wc0] = cvt8(q0, q1);                                               \
    _bp[wc1] = cvt8(q2, q3);                                               \
  } while (0)

// Body granule g: AJ = g&1 (A-f32 buf), BJ = g%3 (B buf), compile-time.
// entry (barrier'd): A-f32[AJ] + B[BJ] resident.
#define BODY(g, AJ, BJ, DOSTAGE, ENDWAIT, ENDBAR)                          \
  do {                                                                     \
    CONV(AJ);                                                              \
    asm volatile("s_waitcnt lgkmcnt(0)" ::: "memory");                     \
    __builtin_amdgcn_s_barrier();       /* Abf16 published */              \
    __builtin_amdgcn_sched_barrier(0);                                     \
    if (DOSTAGE) { STAGE_A((g) + 2, AJ); STAGE_B((g) + 2, ((BJ) + 2) % 3); } \
    const ushort_t* Ar_ = lds + 32768;                                     \
    const ushort_t* Br_ = lds + 40960 + (BJ) * 8192;                       \
    bf16x8 af[8], bfq[4];                                                  \
    _Pragma("unroll") for (int mf = 0; mf < 8; ++mf)                       \
        af[mf] = *(const bf16x8*)(Ar_ + aRd + mf * 512);                   \
    _Pragma("unroll") for (int nf = 0; nf < 4; ++nf)                       \
        bfq[nf] = *(const bf16x8*)(Br_ + bRd + nf * 512);                  \
    asm volatile("s_waitcnt lgkmcnt(0)" ::: "memory");                     \
    __builtin_amdgcn_sched_barrier(0);                                     \
    __builtin_amdgcn_s_setprio(1);                                         \
    _Pragma("unroll") for (int mf = 0; mf < 8; ++mf)                       \
        _Pragma("unroll") for (int nf = 0; nf < 4; ++nf)                   \
            acc[mf][nf] = __builtin_amdgcn_mfma_f32_16x16x32_bf16(         \
                af[mf], bfq[nf], acc[mf][nf], 0, 0, 0);                    \
    __builtin_amdgcn_s_setprio(0);                                         \
    asm volatile(ENDWAIT ::: "memory");                                    \
    if (ENDBAR) { __builtin_amdgcn_s_barrier();                            \
                  __builtin_amdgcn_sched_barrier(0); }                     \
  } while (0)

  // ---- prologue: stage A(0),B(0),A(1),B(1) (12 loads, in order A0 B0 A1
  // B1); vmcnt(6) retires A(0)+B(0), leaves A(1)x4+B(1)x2. ----
  STAGE_A(0, 0); STAGE_B(0, 0);
  STAGE_A(1, 1); STAGE_B(1, 1);
  asm volatile("s_waitcnt vmcnt(6)" ::: "memory");
  __builtin_amdgcn_s_barrier();
  __builtin_amdgcn_sched_barrier(0);

  // ---- main: granules 0..29, period-6 unroll (AJ = g&1, BJ = g%3).
  // End-of-g vmcnt(6): outstanding = g+1's 6 (staged at g-1) + g+2's 6
  // (staged this body) -> retires exactly granule g+1. ----
#pragma unroll 1
  for (int gb = 0; gb < 30; gb += 6) {
    BODY(gb + 0, 0, 0, true, "s_waitcnt vmcnt(6)", true);
    BODY(gb + 1, 1, 1, true, "s_waitcnt vmcnt(6)", true);
    BODY(gb + 2, 0, 2, true, "s_waitcnt vmcnt(6)", true);
    BODY(gb + 3, 1, 0, true, "s_waitcnt vmcnt(6)", true);
    BODY(gb + 4, 0, 1, true, "s_waitcnt vmcnt(6)", true);
    BODY(gb + 5, 1, 2, true, "s_waitcnt vmcnt(6)", true);
  }
  // tails: g30 (AJ=0,BJ=0): no stage; drain remaining (g31's 6) to 0.
  BODY(30, 0, 0, false, "s_waitcnt vmcnt(0)", true);
  // g31 (AJ=1,BJ=1): compute only.
  BODY(31, 1, 1, false, "s_nop 0", false);

#undef BODY
#undef CONV
#undef STAGE_A
#undef STAGE_B

  // ---- epilogue: C/D col = lane&15 (-> e), row = (lane>>4)*4+j (-> m) ----
  const int col = l & 15;
  const int r4  = (l >> 4) * 4;
  float bvv[4];
#pragma unroll
  for (int nf = 0; nf < 4; ++nf)
    bvv[nf] = bias[lsel * EMBED + e0 + wc * 64 + nf * 16 + col];
#pragma unroll
  for (int mf = 0; mf < 8; ++mf) {
#pragma unroll
    for (int j = 0; j < 4; ++j) {
      const size_t ro = (size_t)rowsrc[wr * 128 + mf * 16 + r4 + j] * EMBED;
#pragma unroll
      for (int nf = 0; nf < 4; ++nf)
        out[ro + e0 + wc * 64 + nf * 16 + col] = acc[mf][nf][j] + bvv[nf];
    }
  }
}

// ---------------- Fallback (R2 fused kernel) if ws too small ----------------
__global__ __launch_bounds__(256, 2) void grouped_proj_fused(
    const float* __restrict__ feat, const float* __restrict__ Wt,
    const float* __restrict__ bias, const int* __restrict__ toks,
    float* __restrict__ out)
{
  __shared__ uint4 As[1024];
  __shared__ uint4 Bs[1024];
  __shared__ int tokarr[128];
  __shared__ unsigned long long ballots[2][8];
  __shared__ int perm[128];
  __shared__ int rowsrc[128];

  const int tid  = threadIdx.x;
  const int lane = tid & 63;
  const int wv   = tid >> 6;
  const int wr   = wv >> 1;
  const int wc   = wv & 1;
  const int bid = blockIdx.x;
  const int xcd = bid & 7;
  const int sq  = bid >> 3;
  const int et  = sq & 7;
  const int mt  = (sq >> 3) * 8 + xcd;
  const int m0  = mt * 128;
  const int e0  = et * 128;

  if (tid < 128) tokarr[tid] = toks[tid];
  __syncthreads();
  if (tid < 128) {
    int myt = tokarr[tid];
#pragma unroll
    for (int lg = 0; lg < 8; ++lg) {
      unsigned long long bl = __ballot(myt == lg);
      if (lane == 0) ballots[wv][lg] = bl;
    }
  }
  __syncthreads();
  int lsel = 0, base = 0, csel = 1, boff_sel = 0;
  {
    int cum = 0, boff = 0;
#pragma unroll
    for (int lg = 0; lg < 8; ++lg) {
      int c = __popcll(ballots[0][lg]) + __popcll(ballots[1][lg]);
      int seg = c << 9;
      bool in = (m0 >= cum) && (m0 < cum + seg);
      if (in) { lsel = lg; base = cum; csel = c; boff_sel = boff; }
      cum += seg; boff += c;
    }
  }
  if (tid < 128) {
    int myt = tokarr[tid];
    unsigned long long ltm = (1ull << lane) - 1ull;
    int rank = (wv == 0) ? __popcll(ballots[0][myt] & ltm)
                         : __popcll(ballots[0][myt]) + __popcll(ballots[1][myt] & ltm);
    int boff2 = 0;
#pragma unroll
    for (int lg = 0; lg < 8; ++lg) {
      int c = __popcll(ballots[0][lg]) + __popcll(ballots[1][lg]);
      boff2 += (lg < myt) ? c : 0;
    }
    perm[boff2 + rank] = tid;
  }
  __syncthreads();
  if (tid < 128) {
    int local = m0 - base + tid;
    int s = local / csel;
    int j = local - s * csel;
    rowsrc[tid] = s * BATCH + perm[boff_sel + j];
  }
  __syncthreads();

  int slot_i[4];
  const float* aptr[4];
  const float* bptr[4];
#pragma unroll
  for (int it = 0; it < 4; ++it) {
    int c    = it * 256 + tid;
    int kg   = c & 7;
    int row  = c >> 3;
    int ksub = kg & 3;
    int kk   = kg >> 2;
    int frag = row >> 4;
    slot_i[it] = (kk * 8 + frag) * 64 + ((row & 15) ^ (ksub << 1) ^ kk) + ksub * 16;
    aptr[it] = feat + (size_t)rowsrc[row] * FEAT + kg * 8;
    bptr[it] = Wt + ((size_t)lsel * EMBED + e0 + row) * FEAT + kg * 8;
  }

  f32x4 acc[4][4] = {};
  for (int k0 = 0; k0 < FEAT; k0 += 64) {
    __syncthreads();
#pragma unroll
    for (int it = 0; it < 4; ++it) {
      float4 alo = *(const float4*)(aptr[it] + k0);
      float4 ahi = *(const float4*)(aptr[it] + k0 + 4);
      uint4 av;
      av.x = pk2(alo.x, alo.y); av.y = pk2(alo.z, alo.w);
      av.z = pk2(ahi.x, ahi.y); av.w = pk2(ahi.z, ahi.w);
      As[slot_i[it]] = av;
      float4 blo = *(const float4*)(bptr[it] + k0);
      float4 bhi = *(const float4*)(bptr[it] + k0 + 4);
      uint4 bv;
      bv.x = pk2(blo.x, blo.y); bv.y = pk2(blo.z, blo.w);
      bv.z = pk2(bhi.x, bhi.y); bv.w = pk2(bhi.z, bhi.w);
      Bs[slot_i[it]] = bv;
    }
    __syncthreads();
#pragma unroll
    for (int kk = 0; kk < 2; ++kk) {
      const int ksr = lane >> 4;
      const int sw  = ((lane & 15) ^ (ksr << 1) ^ kk) + ksr * 16;
      bf16x8 af[4], bfr[4];
#pragma unroll
      for (int mi = 0; mi < 4; ++mi)
        af[mi] = ((const bf16x8*)As)[(kk * 8 + wr * 4 + mi) * 64 + sw];
#pragma unroll
      for (int ni = 0; ni < 4; ++ni)
        bfr[ni] = ((const bf16x8*)Bs)[(kk * 8 + wc * 4 + ni) * 64 + sw];
#pragma unroll
      for (int mi = 0; mi < 4; ++mi)
#pragma unroll
        for (int ni = 0; ni < 4; ++ni)
          acc[mi][ni] = __builtin_amdgcn_mfma_f32_16x16x32_bf16(
              af[mi], bfr[ni], acc[mi][ni], 0, 0, 0);
    }
  }

  const int col = lane & 15;
  const int r0  = (lane >> 4) * 4;
  float bvv[4];
#pragma unroll
  for (int ni = 0; ni < 4; ++ni)
    bvv[ni] = bias[lsel * EMBED + e0 + wc * 64 + ni * 16 + col];
#pragma unroll
  for (int mi = 0; mi < 4; ++mi) {
#pragma unroll
    for (int j = 0; j < 4; ++j) {
      const size_t ro = (size_t)rowsrc[wr * 64 + mi * 16 + r0 + j] * EMBED;
#pragma unroll
      for (int ni = 0; ni < 4; ++ni)
        out[ro + e0 + wc * 64 + ni * 16 + col] = acc[mi][ni][j] + bvv[ni];
    }
  }
}

extern "C" void kernel_launch(void* const* d_in, const int* in_sizes, int n_in,
                              void* d_out, int out_size, void* d_ws, size_t ws_size,
                              hipStream_t stream) {
  const float* feat = (const float*)d_in[0];
  const float* W    = (const float*)d_in[1];
  const float* bias = (const float*)d_in[2];
  const int*   toks = (const int*)d_in[3];
  float* out = (float*)d_out;

  const size_t wbf_bytes = (size_t)NLANG * EMBED * FEAT * 2;      // 16 MiB

  if (ws_size >= wbf_bytes) {
    ushort_t* Wbf = (ushort_t*)d_ws;
    convert_w_kernel<<<512, 256, 0, stream>>>(W, Wbf);
    (void)hipFuncSetAttribute((const void*)grouped_gemm_cvt1,
                              hipFuncAttributeMaxDynamicSharedMemorySize, 131072);
    const int nblk = (SEQ * BATCH / 256) * (EMBED / 256);         // 1024
    grouped_gemm_cvt1<<<nblk, 512, 131072, stream>>>(feat, Wbf, bias, toks, out);
  } else {
    grouped_proj_fused<<<(SEQ * BATCH / 128) * (EMBED / 128), 256, 0, stream>>>(
        feat, W, bias, toks, out);
  }
}